// Round 4
// baseline (396.222 us; speedup 1.0000x reference)
//
#include <hip/hip_runtime.h>
#include <hip/hip_bf16.h>

typedef __attribute__((ext_vector_type(8))) short short8;
typedef __attribute__((ext_vector_type(8))) unsigned short ushort8;
typedef __attribute__((ext_vector_type(4))) float f32x4;

#define BUK_SHIFT 7
#define BUK_ROWS 128
#define MAXBUK 400
#define NBLK_BIN 128
#define CAP 8192      // max unpadded edges per bucket (stat bound ~4400)
#define CAP2 6144     // per-bucket stride in padded edge array (max padded ~5300)

static __device__ __forceinline__ unsigned short f2bf(float f) {
    unsigned u = __float_as_uint(f);
    u += 0x7fffu + ((u >> 16) & 1u);
    return (unsigned short)(u >> 16);
}
static __device__ __forceinline__ float bf2f(unsigned short h) {
    return __uint_as_float(((unsigned)h) << 16);
}

__global__ void cvt_kernel(const float* __restrict__ in, unsigned short* __restrict__ out, int n4) {
    int i = blockIdx.x * blockDim.x + threadIdx.x;
    if (i >= n4) return;
    float4 v = reinterpret_cast<const float4*>(in)[i];
    ushort4 o;
    o.x = f2bf(v.x); o.y = f2bf(v.y); o.z = f2bf(v.z); o.w = f2bf(v.w);
    reinterpret_cast<ushort4*>(out)[i] = o;
}

__global__ void wtr_kernel(const float* __restrict__ W, unsigned short* __restrict__ Wt) {
    int k = blockIdx.x, n = threadIdx.x;
    Wt[n * 256 + k] = f2bf(W[k * 256 + n]);
}

// ---- CSR build ----

__global__ __launch_bounds__(1024) void bin_count(const int* __restrict__ rows,
                                                  int* __restrict__ cntM, int E, int nbuk, int ce) {
    __shared__ int c[MAXBUK];
    for (int i = threadIdx.x; i < nbuk; i += 1024) c[i] = 0;
    __syncthreads();
    int s = blockIdx.x * ce, e = s + ce < E ? s + ce : E;
    for (int i = s + (int)threadIdx.x; i < e; i += 1024) atomicAdd(&c[rows[i] >> BUK_SHIFT], 1);
    __syncthreads();
    for (int i = threadIdx.x; i < nbuk; i += 1024) cntM[i * gridDim.x + blockIdx.x] = c[i];
}

__global__ __launch_bounds__(1024) void scan1_kernel(const int* __restrict__ in,
                                                     int* __restrict__ tmp,
                                                     int* __restrict__ bsum, int n) {
    __shared__ int sdata[1024];
    int i = blockIdx.x * 1024 + threadIdx.x;
    int v = (i < n) ? in[i] : 0;
    sdata[threadIdx.x] = v;
    __syncthreads();
    for (int off = 1; off < 1024; off <<= 1) {
        int t = (threadIdx.x >= (unsigned)off) ? sdata[threadIdx.x - off] : 0;
        __syncthreads();
        sdata[threadIdx.x] += t;
        __syncthreads();
    }
    if (i < n) tmp[i] = sdata[threadIdx.x] - v;
    if (threadIdx.x == 1023) bsum[blockIdx.x] = sdata[1023];
}

__global__ void scan2_kernel(const int* __restrict__ bsum, int* __restrict__ boff, int nb) {
    __shared__ int s[64];
    int t = threadIdx.x;
    int v = (t < nb) ? bsum[t] : 0;
    s[t] = v;
    __syncthreads();
    for (int off = 1; off < 64; off <<= 1) {
        int x = (t >= off) ? s[t - off] : 0;
        __syncthreads();
        s[t] += x;
        __syncthreads();
    }
    boff[t] = s[t] - v;
}

__global__ void scan3_kernel(const int* __restrict__ tmp, const int* __restrict__ boff,
                             int* __restrict__ out, int n) {
    int i = blockIdx.x * blockDim.x + threadIdx.x;
    if (i < n) out[i] = tmp[i] + boff[i >> 10];
}

__global__ __launch_bounds__(1024) void bin_scatter(const int* __restrict__ rows,
                                                    const int* __restrict__ cols,
                                                    const float* __restrict__ vals,
                                                    const int* __restrict__ cntS,
                                                    int2* __restrict__ cc,
                                                    unsigned char* __restrict__ rb,
                                                    int E, int nbuk, int ce) {
    __shared__ int cur[MAXBUK];
    for (int i = threadIdx.x; i < nbuk; i += 1024) cur[i] = cntS[i * gridDim.x + blockIdx.x];
    __syncthreads();
    int s = blockIdx.x * ce, e = s + ce < E ? s + ce : E;
    for (int i = s + (int)threadIdx.x; i < e; i += 1024) {
        int r = rows[i];
        int p = atomicAdd(&cur[r >> BUK_SHIFT], 1);
        cc[p] = make_int2(cols[i], __float_as_int(vals[i]));
        rb[p] = (unsigned char)(r & (BUK_ROWS - 1));
    }
}

// per-bucket: degree-sort rows, pad each row to %8 with (0,0), emit rp/perm, write cc2
__global__ __launch_bounds__(1024) void bucket_sort(const int2* __restrict__ cc,
                                                    const unsigned char* __restrict__ rb,
                                                    const int* __restrict__ cntS,
                                                    int2* __restrict__ cc2,
                                                    int2* __restrict__ rp,
                                                    int* __restrict__ perm,
                                                    int E, int nbuk, int nblk, int N) {
    __shared__ unsigned char rloc[CAP];
    __shared__ int cnt[BUK_ROWS];
    __shared__ int rank_of[BUK_ROWS];   // sorted pos -> orig local row
    __shared__ int sortpos[BUK_ROWS];   // orig local row -> sorted pos
    __shared__ int psc[BUK_ROWS];       // inclusive scan of padded counts (sorted order)
    __shared__ int cur[BUK_ROWS];
    const int b = blockIdx.x;
    const int tid = threadIdx.x;
    const int base = cntS[b * nblk];
    const int end = (b + 1 < nbuk) ? cntS[(b + 1) * nblk] : E;
    const int sz = min(end - base, CAP);
    if (tid < BUK_ROWS) cnt[tid] = 0;
    __syncthreads();
    for (int i = tid; i < sz; i += 1024) {
        unsigned char r = rb[base + i];
        rloc[i] = r;
        atomicAdd(&cnt[r], 1);
    }
    __syncthreads();
    if (tid < BUK_ROWS) {
        int c = cnt[tid];
        int rk = 0;
#pragma unroll 8
        for (int j = 0; j < BUK_ROWS; ++j) {
            int cj = cnt[j];
            rk += (cj > c) || (cj == c && j < tid);
        }
        sortpos[tid] = rk;
        rank_of[rk] = tid;
    }
    __syncthreads();
    if (tid < BUK_ROWS) psc[tid] = (cnt[rank_of[tid]] + 7) & ~7;
    __syncthreads();
    for (int off = 1; off < BUK_ROWS; off <<= 1) {
        int t = (tid < BUK_ROWS && tid >= off) ? psc[tid - off] : 0;
        __syncthreads();
        if (tid < BUK_ROWS) psc[tid] += t;
        __syncthreads();
    }
    if (tid < BUK_ROWS) {
        int q = sortpos[tid];
        int pc = (cnt[tid] + 7) & ~7;
        int excl = psc[q] - pc;
        cur[tid] = excl;
        int g = b * BUK_ROWS + q;
        rp[g] = make_int2(b * CAP2 + excl, b * CAP2 + excl + pc);
        perm[g] = b * BUK_ROWS + tid;
    }
    __syncthreads();
    for (int i = tid; i < sz; i += 1024) {
        int p = atomicAdd(&cur[rloc[i]], 1);
        if (p < CAP2) cc2[(size_t)b * CAP2 + p] = cc[base + i];
    }
}

// C[M][256] = A[M][256] @ Bt[n][k]^T   (bf16 in/out, f32 accum)
__global__ __launch_bounds__(256) void gemm_kernel(const unsigned short* __restrict__ A,
                                                   const unsigned short* __restrict__ Bt,
                                                   unsigned short* __restrict__ C, int M) {
    const int lane = threadIdx.x & 63;
    const int wave = threadIdx.x >> 6;
    const int m0 = blockIdx.x * 64;
    const int n0 = wave * 64;
    const int l15 = lane & 15;
    const int lk = (lane >> 4) * 8;
    f32x4 acc[4][4] = {};
    const unsigned short* aptr[4];
    const unsigned short* bptr[4];
#pragma unroll
    for (int mf = 0; mf < 4; ++mf) {
        int row = m0 + mf * 16 + l15;
        aptr[mf] = A + (size_t)(row < M ? row : 0) * 256 + lk;
    }
#pragma unroll
    for (int nf = 0; nf < 4; ++nf) bptr[nf] = Bt + (size_t)(n0 + nf * 16 + l15) * 256 + lk;
    for (int kk = 0; kk < 256; kk += 32) {
        short8 a[4], b[4];
#pragma unroll
        for (int mf = 0; mf < 4; ++mf) a[mf] = *reinterpret_cast<const short8*>(aptr[mf] + kk);
#pragma unroll
        for (int nf = 0; nf < 4; ++nf) b[nf] = *reinterpret_cast<const short8*>(bptr[nf] + kk);
#pragma unroll
        for (int mf = 0; mf < 4; ++mf)
#pragma unroll
            for (int nf = 0; nf < 4; ++nf)
                acc[mf][nf] = __builtin_amdgcn_mfma_f32_16x16x32_bf16(a[mf], b[nf], acc[mf][nf], 0, 0, 0);
    }
#pragma unroll
    for (int mf = 0; mf < 4; ++mf) {
#pragma unroll
        for (int r = 0; r < 4; ++r) {
            int row = m0 + mf * 16 + (lane >> 4) * 4 + r;
            if (row < M) {
#pragma unroll
                for (int nf = 0; nf < 4; ++nf)
                    C[(size_t)row * 256 + n0 + nf * 16 + l15] = f2bf(acc[mf][nf][r]);
            }
        }
    }
}

// SpMM: 2 work-items per wave; half-wave owns a row; lane owns 8 feats; no predication
template <int LAYER2>
__global__ __launch_bounds__(256) void spmm_kernel(const unsigned short* __restrict__ S,
                                                   const int2* __restrict__ rp,
                                                   const int* __restrict__ perm,
                                                   const int2* __restrict__ cc,
                                                   const float* __restrict__ bias,
                                                   unsigned short* __restrict__ out_bf,
                                                   float* __restrict__ out_f,
                                                   const int* __restrict__ pos_idx, int N) {
    const int lane = threadIdx.x & 63;
    const int wid = threadIdx.x >> 6;
    const int half = lane >> 5;
    const int l = lane & 31;
    const int g = blockIdx.x * 8 + wid * 2 + half;
    const int2 r = rp[g];
    const int row = perm[g];
    const int s = r.x, e = r.y;
    float a0 = 0.f, a1 = 0.f, a2 = 0.f, a3 = 0.f, a4 = 0.f, a5 = 0.f, a6 = 0.f, a7 = 0.f;
    const unsigned short* Sl = S + l * 8;
    for (int i = s; i < e; i += 8) {
        int4 q0 = *reinterpret_cast<const int4*>(cc + i);
        int4 q1 = *reinterpret_cast<const int4*>(cc + i + 2);
        int4 q2 = *reinterpret_cast<const int4*>(cc + i + 4);
        int4 q3 = *reinterpret_cast<const int4*>(cc + i + 6);
        ushort8 u0 = *reinterpret_cast<const ushort8*>(Sl + ((size_t)q0.x << 8));
        ushort8 u1 = *reinterpret_cast<const ushort8*>(Sl + ((size_t)q0.z << 8));
        ushort8 u2 = *reinterpret_cast<const ushort8*>(Sl + ((size_t)q1.x << 8));
        ushort8 u3 = *reinterpret_cast<const ushort8*>(Sl + ((size_t)q1.z << 8));
        ushort8 u4 = *reinterpret_cast<const ushort8*>(Sl + ((size_t)q2.x << 8));
        ushort8 u5 = *reinterpret_cast<const ushort8*>(Sl + ((size_t)q2.z << 8));
        ushort8 u6 = *reinterpret_cast<const ushort8*>(Sl + ((size_t)q3.x << 8));
        ushort8 u7 = *reinterpret_cast<const ushort8*>(Sl + ((size_t)q3.z << 8));
        float v0 = __int_as_float(q0.y), v1 = __int_as_float(q0.w);
        float v2 = __int_as_float(q1.y), v3 = __int_as_float(q1.w);
        float v4 = __int_as_float(q2.y), v5 = __int_as_float(q2.w);
        float v6 = __int_as_float(q3.y), v7 = __int_as_float(q3.w);
#define ACC(uu, vv) \
        a0 += vv * bf2f(uu[0]); a1 += vv * bf2f(uu[1]); a2 += vv * bf2f(uu[2]); a3 += vv * bf2f(uu[3]); \
        a4 += vv * bf2f(uu[4]); a5 += vv * bf2f(uu[5]); a6 += vv * bf2f(uu[6]); a7 += vv * bf2f(uu[7]);
        ACC(u0, v0) ACC(u1, v1) ACC(u2, v2) ACC(u3, v3)
        ACC(u4, v4) ACC(u5, v5) ACC(u6, v6) ACC(u7, v7)
#undef ACC
    }
    if (row >= N) return;
    const int f = l * 8;
    a0 = fmaxf(a0 + bias[f + 0], 0.f);
    a1 = fmaxf(a1 + bias[f + 1], 0.f);
    a2 = fmaxf(a2 + bias[f + 2], 0.f);
    a3 = fmaxf(a3 + bias[f + 3], 0.f);
    a4 = fmaxf(a4 + bias[f + 4], 0.f);
    a5 = fmaxf(a5 + bias[f + 5], 0.f);
    a6 = fmaxf(a6 + bias[f + 6], 0.f);
    a7 = fmaxf(a7 + bias[f + 7], 0.f);
    if (LAYER2) {
        int orow = pos_idx[row];
        float* o = out_f + (size_t)orow * 256 + f;
        *reinterpret_cast<float4*>(o) = make_float4(a0, a1, a2, a3);
        *reinterpret_cast<float4*>(o + 4) = make_float4(a4, a5, a6, a7);
    } else {
        ushort8 o;
        o[0] = f2bf(a0); o[1] = f2bf(a1); o[2] = f2bf(a2); o[3] = f2bf(a3);
        o[4] = f2bf(a4); o[5] = f2bf(a5); o[6] = f2bf(a6); o[7] = f2bf(a7);
        *reinterpret_cast<ushort8*>(out_bf + (size_t)row * 256 + f) = o;
    }
}

extern "C" void kernel_launch(void* const* d_in, const int* in_sizes, int n_in,
                              void* d_out, int out_size, void* d_ws, size_t ws_size,
                              hipStream_t stream) {
    const float* x        = (const float*)d_in[0];
    const int* adj_rows   = (const int*)d_in[1];
    const int* adj_cols   = (const int*)d_in[2];
    const float* adj_vals = (const float*)d_in[3];
    const int* pos_idx    = (const int*)d_in[5];
    const float* W1       = (const float*)d_in[6];
    const float* b1       = (const float*)d_in[7];
    const float* W2       = (const float*)d_in[8];
    const float* b2       = (const float*)d_in[9];

    const int N = in_sizes[0] / 256;
    const int E = in_sizes[1];
    const int nbuk = (N + BUK_ROWS - 1) >> BUK_SHIFT;       // 391
    const int n2 = nbuk * NBLK_BIN;
    const int nb2 = (n2 + 1023) / 1024;
    const int ce = (E + NBLK_BIN - 1) / NBLK_BIN;
    const int nwork = nbuk * BUK_ROWS;                      // 50048

    char* ws = (char*)d_ws;
    size_t off = 0;
    auto alloc = [&](size_t bytes) {
        char* p = ws + off;
        off += (bytes + 255) & ~(size_t)255;
        return p;
    };
    unsigned short* xb   = (unsigned short*)alloc((size_t)N * 256 * 2); // cc aliases this (CSR phase)
    unsigned short* supb = (unsigned short*)alloc((size_t)N * 256 * 2); // rb aliases this
    unsigned short* w1t  = (unsigned short*)alloc(256 * 256 * 2);
    unsigned short* w2t  = (unsigned short*)alloc(256 * 256 * 2);
    int2* rp     = (int2*)alloc((size_t)nwork * 8);
    int* perm    = (int*)alloc((size_t)nwork * 4);
    int* cntM    = (int*)alloc((size_t)n2 * 4);
    int* cntS    = (int*)alloc((size_t)n2 * 4);
    int* tmp     = (int*)alloc((size_t)n2 * 4);
    int* bsum    = (int*)alloc(64 * 4);
    int* boff    = (int*)alloc(64 * 4);
    int2* cc2    = (int2*)alloc((size_t)nbuk * CAP2 * 8);
    int2* cc     = (int2*)xb;          // alias: dead once bucket_sort completes
    unsigned char* rb = (unsigned char*)supb; // alias: dead once bucket_sort completes
    (void)ws_size; (void)n_in;

    hipMemsetAsync(d_out, 0, (size_t)out_size * 4, stream);
    hipMemsetAsync(cc2, 0, (size_t)nbuk * CAP2 * 8, stream);

    // CSR build (uses xb/supb space as scratch)
    bin_count<<<NBLK_BIN, 1024, 0, stream>>>(adj_rows, cntM, E, nbuk, ce);
    scan1_kernel<<<nb2, 1024, 0, stream>>>(cntM, tmp, bsum, n2);
    scan2_kernel<<<1, 64, 0, stream>>>(bsum, boff, nb2);
    scan3_kernel<<<(n2 + 255) / 256, 256, 0, stream>>>(tmp, boff, cntS, n2);
    bin_scatter<<<NBLK_BIN, 1024, 0, stream>>>(adj_rows, adj_cols, adj_vals, cntS, cc, rb, E, nbuk, ce);
    bucket_sort<<<nbuk, 1024, 0, stream>>>(cc, rb, cntS, cc2, rp, perm, E, nbuk, NBLK_BIN, N);

    // now xb/supb are free for dense use
    cvt_kernel<<<(N * 64 + 255) / 256, 256, 0, stream>>>(x, xb, N * 64);
    wtr_kernel<<<256, 256, 0, stream>>>(W1, w1t);
    wtr_kernel<<<256, 256, 0, stream>>>(W2, w2t);

    const int ggrid = (N + 63) / 64;
    const int sgrid = nwork / 8;
    // layer 1
    gemm_kernel<<<ggrid, 256, 0, stream>>>(xb, w1t, supb, N);
    spmm_kernel<0><<<sgrid, 256, 0, stream>>>(supb, rp, perm, cc2, b1, xb, nullptr, nullptr, N);
    // layer 2
    gemm_kernel<<<ggrid, 256, 0, stream>>>(xb, w2t, supb, N);
    spmm_kernel<1><<<sgrid, 256, 0, stream>>>(supb, rp, perm, cc2, b2, nullptr, (float*)d_out, pos_idx, N);
}

// Round 5
// 264.560 us; speedup vs baseline: 1.4977x; 1.4977x over previous
//
#include <hip/hip_runtime.h>
#include <hip/hip_bf16.h>

typedef __attribute__((ext_vector_type(8))) short short8;
typedef __attribute__((ext_vector_type(8))) unsigned short ushort8;
typedef __attribute__((ext_vector_type(4))) float f32x4;
typedef __attribute__((ext_vector_type(2))) float f32x2;

#define BUK_SHIFT 7
#define BUK_ROWS 128
#define MAXBUK 400
#define NBLK_BIN 128
#define CAP2 6144     // per-bucket stride in padded edge array (expected ~4100+pads)

static __device__ __forceinline__ unsigned short f2bf(float f) {
    unsigned u = __float_as_uint(f);
    u += 0x7fffu + ((u >> 16) & 1u);
    return (unsigned short)(u >> 16);
}

__global__ void cvt_kernel(const float* __restrict__ in, unsigned short* __restrict__ out, int n4) {
    int i = blockIdx.x * blockDim.x + threadIdx.x;
    if (i >= n4) return;
    float4 v = reinterpret_cast<const float4*>(in)[i];
    ushort4 o;
    o.x = f2bf(v.x); o.y = f2bf(v.y); o.z = f2bf(v.z); o.w = f2bf(v.w);
    reinterpret_cast<ushort4*>(out)[i] = o;
}

__global__ void wtr_kernel(const float* __restrict__ W, unsigned short* __restrict__ Wt) {
    int k = blockIdx.x, n = threadIdx.x;
    Wt[n * 256 + k] = f2bf(W[k * 256 + n]);
}

// ---- CSR build (two-level binning; natural row order; rows padded to %8) ----

__global__ __launch_bounds__(1024) void bin_count(const int* __restrict__ rows,
                                                  int* __restrict__ cntM, int E, int nbuk, int ce) {
    __shared__ int c[MAXBUK];
    for (int i = threadIdx.x; i < nbuk; i += 1024) c[i] = 0;
    __syncthreads();
    int s = blockIdx.x * ce, e = s + ce < E ? s + ce : E;
    for (int i = s + (int)threadIdx.x; i < e; i += 1024) atomicAdd(&c[rows[i] >> BUK_SHIFT], 1);
    __syncthreads();
    for (int i = threadIdx.x; i < nbuk; i += 1024) cntM[i * gridDim.x + blockIdx.x] = c[i];
}

__global__ __launch_bounds__(1024) void scan1_kernel(const int* __restrict__ in,
                                                     int* __restrict__ tmp,
                                                     int* __restrict__ bsum, int n) {
    __shared__ int sdata[1024];
    int i = blockIdx.x * 1024 + threadIdx.x;
    int v = (i < n) ? in[i] : 0;
    sdata[threadIdx.x] = v;
    __syncthreads();
    for (int off = 1; off < 1024; off <<= 1) {
        int t = (threadIdx.x >= (unsigned)off) ? sdata[threadIdx.x - off] : 0;
        __syncthreads();
        sdata[threadIdx.x] += t;
        __syncthreads();
    }
    if (i < n) tmp[i] = sdata[threadIdx.x] - v;
    if (threadIdx.x == 1023) bsum[blockIdx.x] = sdata[1023];
}

__global__ void scan2_kernel(const int* __restrict__ bsum, int* __restrict__ boff, int nb) {
    __shared__ int s[64];
    int t = threadIdx.x;
    int v = (t < nb) ? bsum[t] : 0;
    s[t] = v;
    __syncthreads();
    for (int off = 1; off < 64; off <<= 1) {
        int x = (t >= off) ? s[t - off] : 0;
        __syncthreads();
        s[t] += x;
        __syncthreads();
    }
    boff[t] = s[t] - v;
}

__global__ void scan3_kernel(const int* __restrict__ tmp, const int* __restrict__ boff,
                             int* __restrict__ out, int n) {
    int i = blockIdx.x * blockDim.x + threadIdx.x;
    if (i < n) out[i] = tmp[i] + boff[i >> 10];
}

__global__ __launch_bounds__(1024) void bin_scatter(const int* __restrict__ rows,
                                                    const int* __restrict__ cols,
                                                    const float* __restrict__ vals,
                                                    const int* __restrict__ cntS,
                                                    int2* __restrict__ cc,
                                                    unsigned char* __restrict__ rb,
                                                    int E, int nbuk, int ce) {
    __shared__ int cur[MAXBUK];
    for (int i = threadIdx.x; i < nbuk; i += 1024) cur[i] = cntS[i * gridDim.x + blockIdx.x];
    __syncthreads();
    int s = blockIdx.x * ce, e = s + ce < E ? s + ce : E;
    for (int i = s + (int)threadIdx.x; i < e; i += 1024) {
        int r = rows[i];
        int p = atomicAdd(&cur[r >> BUK_SHIFT], 1);
        cc[p] = make_int2(cols[i], __float_as_int(vals[i]));
        rb[p] = (unsigned char)(r & (BUK_ROWS - 1));
    }
}

// per-bucket: natural row order, pad each row to %8 with (col=0,val=0); emit rp; write cc2
__global__ __launch_bounds__(1024) void bucket_pad(const int2* __restrict__ cc,
                                                   const unsigned char* __restrict__ rb,
                                                   const int* __restrict__ cntS,
                                                   int2* __restrict__ cc2,
                                                   int2* __restrict__ rp,
                                                   int E, int nbuk, int nblk, int N) {
    __shared__ int cnt[BUK_ROWS];
    __shared__ int psc[BUK_ROWS];
    __shared__ int cur[BUK_ROWS];
    const int b = blockIdx.x;
    const int tid = threadIdx.x;
    const int base = cntS[b * nblk];
    const int end = (b + 1 < nbuk) ? cntS[(b + 1) * nblk] : E;
    const int sz = end - base;
    if (tid < BUK_ROWS) cnt[tid] = 0;
    __syncthreads();
    for (int i = tid; i < sz; i += 1024) atomicAdd(&cnt[rb[base + i]], 1);
    __syncthreads();
    if (tid < BUK_ROWS) psc[tid] = (cnt[tid] + 7) & ~7;
    __syncthreads();
    for (int off = 1; off < BUK_ROWS; off <<= 1) {
        int t = (tid < BUK_ROWS && tid >= off) ? psc[tid - off] : 0;
        __syncthreads();
        if (tid < BUK_ROWS) psc[tid] += t;
        __syncthreads();
    }
    if (tid < BUK_ROWS) {
        int c = cnt[tid];
        int pc = (c + 7) & ~7;
        int excl = psc[tid] - pc;
        cur[tid] = excl;
        int st = b * CAP2 + excl;
        rp[b * BUK_ROWS + tid] = make_int2(st, st + pc);
        for (int z = c; z < pc; ++z) cc2[(size_t)st + z] = make_int2(0, 0);  // pad slots
    }
    __syncthreads();
    for (int i = tid; i < sz; i += 1024) {
        int p = atomicAdd(&cur[rb[base + i]], 1);
        cc2[(size_t)b * CAP2 + p] = cc[base + i];
    }
}

// S8[m][n] (fp8 e4m3) = fp8(A[m][256] @ Bt[n][256]^T), bf16 in, f32 accum.
// transposed-operand MFMA: mfma(b,a) -> D[n via reg][m via lane&15], so each lane
// holds 4 CONSECUTIVE features of one node -> in-register fp8 pack, dword store.
__global__ __launch_bounds__(256) void gemm_kernel(const unsigned short* __restrict__ A,
                                                   const unsigned short* __restrict__ Bt,
                                                   unsigned char* __restrict__ S8, int M) {
    const int lane = threadIdx.x & 63;
    const int wave = threadIdx.x >> 6;
    const int m0 = blockIdx.x * 64;
    const int n0 = wave * 64;
    const int l15 = lane & 15;
    const int lk = (lane >> 4) * 8;
    f32x4 acc[4][4] = {};
    const unsigned short* aptr[4];
    const unsigned short* bptr[4];
#pragma unroll
    for (int mf = 0; mf < 4; ++mf) {
        int row = m0 + mf * 16 + l15;
        aptr[mf] = A + (size_t)(row < M ? row : 0) * 256 + lk;
    }
#pragma unroll
    for (int nf = 0; nf < 4; ++nf) bptr[nf] = Bt + (size_t)(n0 + nf * 16 + l15) * 256 + lk;
    for (int kk = 0; kk < 256; kk += 32) {
        short8 a[4], b[4];
#pragma unroll
        for (int mf = 0; mf < 4; ++mf) a[mf] = *reinterpret_cast<const short8*>(aptr[mf] + kk);
#pragma unroll
        for (int nf = 0; nf < 4; ++nf) b[nf] = *reinterpret_cast<const short8*>(bptr[nf] + kk);
#pragma unroll
        for (int mf = 0; mf < 4; ++mf)
#pragma unroll
            for (int nf = 0; nf < 4; ++nf)
                acc[mf][nf] = __builtin_amdgcn_mfma_f32_16x16x32_bf16(b[nf], a[mf], acc[mf][nf], 0, 0, 0);
    }
    const int g4 = (lane >> 4) * 4;
#pragma unroll
    for (int mf = 0; mf < 4; ++mf) {
        int m = m0 + mf * 16 + l15;
        if (m < M) {
#pragma unroll
            for (int nf = 0; nf < 4; ++nf) {
                int p = __builtin_amdgcn_cvt_pk_fp8_f32(acc[mf][nf][0], acc[mf][nf][1], 0, false);
                p = __builtin_amdgcn_cvt_pk_fp8_f32(acc[mf][nf][2], acc[mf][nf][3], p, true);
                *reinterpret_cast<int*>(S8 + (size_t)m * 256 + n0 + nf * 16 + g4) = p;
            }
        }
    }
}

// SpMM: half-wave owns a row; lane owns 8 feats (8B fp8 gathers); padded rows, no predication
template <int LAYER2>
__global__ __launch_bounds__(256) void spmm_kernel(const unsigned char* __restrict__ S8,
                                                   const int2* __restrict__ rp,
                                                   const int2* __restrict__ cc,
                                                   const float* __restrict__ bias,
                                                   unsigned short* __restrict__ out_bf,
                                                   float* __restrict__ out_f,
                                                   const int* __restrict__ pos_idx, int N) {
    const int lane = threadIdx.x & 63;
    const int wid = threadIdx.x >> 6;
    const int half = lane >> 5;
    const int l = lane & 31;
    const int row = blockIdx.x * 8 + wid * 2 + half;
    const int2 r = rp[row];
    const int s = r.x, e = r.y;
    float a0 = 0.f, a1 = 0.f, a2 = 0.f, a3 = 0.f, a4 = 0.f, a5 = 0.f, a6 = 0.f, a7 = 0.f;
    const unsigned char* Sl = S8 + l * 8;
    for (int i = s; i < e; i += 8) {
        int4 q0 = *reinterpret_cast<const int4*>(cc + i);
        int4 q1 = *reinterpret_cast<const int4*>(cc + i + 2);
        int4 q2 = *reinterpret_cast<const int4*>(cc + i + 4);
        int4 q3 = *reinterpret_cast<const int4*>(cc + i + 6);
        uint2 u0 = *reinterpret_cast<const uint2*>(Sl + ((size_t)q0.x << 8));
        uint2 u1 = *reinterpret_cast<const uint2*>(Sl + ((size_t)q0.z << 8));
        uint2 u2 = *reinterpret_cast<const uint2*>(Sl + ((size_t)q1.x << 8));
        uint2 u3 = *reinterpret_cast<const uint2*>(Sl + ((size_t)q1.z << 8));
        uint2 u4 = *reinterpret_cast<const uint2*>(Sl + ((size_t)q2.x << 8));
        uint2 u5 = *reinterpret_cast<const uint2*>(Sl + ((size_t)q2.z << 8));
        uint2 u6 = *reinterpret_cast<const uint2*>(Sl + ((size_t)q3.x << 8));
        uint2 u7 = *reinterpret_cast<const uint2*>(Sl + ((size_t)q3.z << 8));
        float v0 = __int_as_float(q0.y), v1 = __int_as_float(q0.w);
        float v2 = __int_as_float(q1.y), v3 = __int_as_float(q1.w);
        float v4 = __int_as_float(q2.y), v5 = __int_as_float(q2.w);
        float v6 = __int_as_float(q3.y), v7 = __int_as_float(q3.w);
#define ACC(uu, vv) { \
        f32x2 p01 = __builtin_amdgcn_cvt_pk_f32_fp8((int)uu.x, false); \
        f32x2 p23 = __builtin_amdgcn_cvt_pk_f32_fp8((int)uu.x, true);  \
        f32x2 p45 = __builtin_amdgcn_cvt_pk_f32_fp8((int)uu.y, false); \
        f32x2 p67 = __builtin_amdgcn_cvt_pk_f32_fp8((int)uu.y, true);  \
        a0 += vv * p01.x; a1 += vv * p01.y; a2 += vv * p23.x; a3 += vv * p23.y; \
        a4 += vv * p45.x; a5 += vv * p45.y; a6 += vv * p67.x; a7 += vv * p67.y; }
        ACC(u0, v0) ACC(u1, v1) ACC(u2, v2) ACC(u3, v3)
        ACC(u4, v4) ACC(u5, v5) ACC(u6, v6) ACC(u7, v7)
#undef ACC
    }
    if (row >= N) return;
    const int f = l * 8;
    a0 = fmaxf(a0 + bias[f + 0], 0.f);
    a1 = fmaxf(a1 + bias[f + 1], 0.f);
    a2 = fmaxf(a2 + bias[f + 2], 0.f);
    a3 = fmaxf(a3 + bias[f + 3], 0.f);
    a4 = fmaxf(a4 + bias[f + 4], 0.f);
    a5 = fmaxf(a5 + bias[f + 5], 0.f);
    a6 = fmaxf(a6 + bias[f + 6], 0.f);
    a7 = fmaxf(a7 + bias[f + 7], 0.f);
    if (LAYER2) {
        int orow = pos_idx[row];
        float* o = out_f + (size_t)orow * 256 + f;
        *reinterpret_cast<float4*>(o) = make_float4(a0, a1, a2, a3);
        *reinterpret_cast<float4*>(o + 4) = make_float4(a4, a5, a6, a7);
    } else {
        ushort8 o;
        o[0] = f2bf(a0); o[1] = f2bf(a1); o[2] = f2bf(a2); o[3] = f2bf(a3);
        o[4] = f2bf(a4); o[5] = f2bf(a5); o[6] = f2bf(a6); o[7] = f2bf(a7);
        *reinterpret_cast<ushort8*>(out_bf + (size_t)row * 256 + f) = o;
    }
}

extern "C" void kernel_launch(void* const* d_in, const int* in_sizes, int n_in,
                              void* d_out, int out_size, void* d_ws, size_t ws_size,
                              hipStream_t stream) {
    const float* x        = (const float*)d_in[0];
    const int* adj_rows   = (const int*)d_in[1];
    const int* adj_cols   = (const int*)d_in[2];
    const float* adj_vals = (const float*)d_in[3];
    const int* pos_idx    = (const int*)d_in[5];
    const float* W1       = (const float*)d_in[6];
    const float* b1       = (const float*)d_in[7];
    const float* W2       = (const float*)d_in[8];
    const float* b2       = (const float*)d_in[9];

    const int N = in_sizes[0] / 256;
    const int E = in_sizes[1];
    const int nbuk = (N + BUK_ROWS - 1) >> BUK_SHIFT;       // 391
    const int n2 = nbuk * NBLK_BIN;
    const int nb2 = (n2 + 1023) / 1024;
    const int ce = (E + NBLK_BIN - 1) / NBLK_BIN;
    const int nwork = nbuk * BUK_ROWS;                      // 50048

    char* ws = (char*)d_ws;
    size_t off = 0;
    auto alloc = [&](size_t bytes) {
        char* p = ws + off;
        off += (bytes + 255) & ~(size_t)255;
        return p;
    };
    unsigned short* xb   = (unsigned short*)alloc((size_t)N * 256 * 2); // x bf16, reused as h
    unsigned char*  sup8 = (unsigned char*)alloc((size_t)N * 256);      // fp8 support
    unsigned short* w1t  = (unsigned short*)alloc(256 * 256 * 2);
    unsigned short* w2t  = (unsigned short*)alloc(256 * 256 * 2);
    int2* rp     = (int2*)alloc((size_t)nwork * 8);
    int* cntM    = (int*)alloc((size_t)n2 * 4);
    int* cntS    = (int*)alloc((size_t)n2 * 4);
    int* tmp     = (int*)alloc((size_t)n2 * 4);
    int* bsum    = (int*)alloc(64 * 4);
    int* boff    = (int*)alloc(64 * 4);
    int2* cc     = (int2*)alloc((size_t)E * 8);
    unsigned char* rb = (unsigned char*)alloc((size_t)E);
    int2* cc2    = (int2*)alloc((size_t)nbuk * CAP2 * 8);
    (void)ws_size; (void)n_in;

    // only rows [N, PAD_N) need zeroing: spmm layer-2 writes all rows pos_idx[0..N) fully
    hipMemsetAsync((float*)d_out + (size_t)N * 256, 0,
                   ((size_t)out_size - (size_t)N * 256) * 4, stream);

    cvt_kernel<<<(N * 64 + 255) / 256, 256, 0, stream>>>(x, xb, N * 64);
    wtr_kernel<<<256, 256, 0, stream>>>(W1, w1t);
    wtr_kernel<<<256, 256, 0, stream>>>(W2, w2t);

    // CSR build (natural order, padded)
    bin_count<<<NBLK_BIN, 1024, 0, stream>>>(adj_rows, cntM, E, nbuk, ce);
    scan1_kernel<<<nb2, 1024, 0, stream>>>(cntM, tmp, bsum, n2);
    scan2_kernel<<<1, 64, 0, stream>>>(bsum, boff, nb2);
    scan3_kernel<<<(n2 + 255) / 256, 256, 0, stream>>>(tmp, boff, cntS, n2);
    bin_scatter<<<NBLK_BIN, 1024, 0, stream>>>(adj_rows, adj_cols, adj_vals, cntS, cc, rb, E, nbuk, ce);
    bucket_pad<<<nbuk, 1024, 0, stream>>>(cc, rb, cntS, cc2, rp, E, nbuk, NBLK_BIN, N);

    const int ggrid = (N + 63) / 64;
    const int sgrid = nwork / 8;
    // layer 1
    gemm_kernel<<<ggrid, 256, 0, stream>>>(xb, w1t, sup8, N);
    spmm_kernel<0><<<sgrid, 256, 0, stream>>>(sup8, rp, cc2, b1, xb, nullptr, nullptr, N);
    // layer 2
    gemm_kernel<<<ggrid, 256, 0, stream>>>(xb, w2t, sup8, N);
    spmm_kernel<1><<<sgrid, 256, 0, stream>>>(sup8, rp, cc2, b2, nullptr, (float*)d_out, pos_idx, N);
}